// Round 1
// baseline (205.182 us; speedup 1.0000x reference)
//
#include <hip/hip_runtime.h>
#include <math.h>

#define G_GAMES 8
#define D_IN 512
#define H1 1024
#define H2 1024
#define A_DIM 128
#define B_ROWS 8192

typedef short bf16x8 __attribute__((ext_vector_type(8)));
typedef float f32x4 __attribute__((ext_vector_type(4)));

// ---------- workspace layout (bytes) ----------
#define WS_OFF   0u                                   // 16 ints
#define WS_PERM  256u                                 // 8192 ints
#define WS_SPERM 33280u                               // B*D_IN bf16 = 8388608
#define WS_W1T   (WS_SPERM + B_ROWS*D_IN*2u)          // 8421888, G*H1*D_IN bf16 = 8388608
#define WS_W2T   (WS_W1T + G_GAMES*D_IN*H1*2u)        // 16810496, H2*H1 bf16 = 2097152
#define WS_W3T   (WS_W2T + (unsigned)H1*H2*2u)        // 18907648, G*A*H2 bf16 = 2097152
#define WS_H1    (WS_W3T + G_GAMES*H2*A_DIM*2u)       // 21004800, B*H1 bf16 = 16777216
#define WS_HF    WS_SPERM                             // aliases sPerm+W1T (dead after gemm1)
// total required: 37,782,016 bytes

__device__ __forceinline__ unsigned short f2bf(float x) {
  union { float f; unsigned int u; } v; v.f = x;
  unsigned int r = v.u + 0x7fffu + ((v.u >> 16) & 1u);
  return (unsigned short)(r >> 16);
}

__device__ __forceinline__ void async_load16(const void* gptr, void* ldsptr) {
  __builtin_amdgcn_global_load_lds(
      (const __attribute__((address_space(1))) unsigned int*)gptr,
      (__attribute__((address_space(3))) unsigned int*)ldsptr,
      16, 0, 0);
}

// ---------------- stable counting sort of idx (B=8192, G=8) ----------------
__global__ __launch_bounds__(1024) void k_sort(const int* __restrict__ idx,
                                               int* __restrict__ perm,
                                               int* __restrict__ off) {
  __shared__ int cnts[1024 * 9];  // stride 9 to dodge bank conflicts
  const int t = threadIdx.x;
  int my[8];
  int local[8] = {0, 0, 0, 0, 0, 0, 0, 0};
#pragma unroll
  for (int i = 0; i < 8; ++i) {
    my[i] = idx[t * 8 + i];
    local[my[i]]++;
  }
#pragma unroll
  for (int g = 0; g < 8; ++g) cnts[t * 9 + g] = local[g];
  __syncthreads();
  for (int d = 1; d < 1024; d <<= 1) {
    int v[8];
    const bool act = (t >= d);
    if (act) {
#pragma unroll
      for (int g = 0; g < 8; ++g) v[g] = cnts[(t - d) * 9 + g];
    }
    __syncthreads();
    if (act) {
#pragma unroll
      for (int g = 0; g < 8; ++g) cnts[t * 9 + g] += v[g];
    }
    __syncthreads();
  }
  int offg[9];
  offg[0] = 0;
#pragma unroll
  for (int g = 0; g < 8; ++g) offg[g + 1] = offg[g] + cnts[1023 * 9 + g];
  int start[8];
#pragma unroll
  for (int g = 0; g < 8; ++g) start[g] = offg[g] + cnts[t * 9 + g] - local[g];
#pragma unroll
  for (int i = 0; i < 8; ++i) {
    const int g = my[i];
    perm[start[g]++] = t * 8 + i;
  }
  if (t == 0) {
#pragma unroll
    for (int g = 0; g < 9; ++g) off[g] = offg[g];
  }
}

// ------------- batched fp32 [R][C] -> bf16 [C][R] transpose (64x64 tiles) -------------
__global__ __launch_bounds__(256) void k_transpose(const float* __restrict__ in,
                                                   unsigned short* __restrict__ out,
                                                   int R, int C) {
  in  += (size_t)blockIdx.z * R * C;
  out += (size_t)blockIdx.z * R * C;
  __shared__ float tile[64][65];
  const int c0 = blockIdx.x * 64, r0 = blockIdx.y * 64;
  const int tx = threadIdx.x & 63, ty = threadIdx.x >> 6;
#pragma unroll
  for (int rr = ty; rr < 64; rr += 4)
    tile[rr][tx] = in[(size_t)(r0 + rr) * C + c0 + tx];
  __syncthreads();
#pragma unroll
  for (int cc = ty; cc < 64; cc += 4)
    out[(size_t)(c0 + cc) * R + r0 + tx] = f2bf(tile[tx][cc]);
}

// ------------- gather state rows by perm, fp32 -> bf16 -------------
__global__ __launch_bounds__(256) void k_gather(const float* __restrict__ state,
                                                const int* __restrict__ perm,
                                                unsigned short* __restrict__ sPerm) {
  const int p = blockIdx.x * 2 + (threadIdx.x >> 7);
  const int c = (threadIdx.x & 127) << 2;
  const int src = perm[p];
  const float4 v = *(const float4*)(state + (size_t)src * D_IN + c);
  ushort4 o;
  o.x = f2bf(v.x); o.y = f2bf(v.y); o.z = f2bf(v.z); o.w = f2bf(v.w);
  *(ushort4*)(sPerm + (size_t)p * D_IN + c) = o;
}

// ------------- shared MFMA GEMM core: 128x128 tile, BK=64, 4 waves 2x2, 4x4 accs -------------
// LDS layout: per row 8x16B units, physical unit = logical ^ (row&7)  (<=2-way bank aliasing)
__device__ __forceinline__ void gemm_mfma_core(const unsigned short* const* aRow,
                                               const unsigned short* const* bRow,
                                               unsigned short* ldsA, unsigned short* ldsB,
                                               int KTOT, int tid, f32x4 acc[4][4]) {
  const int lane = tid & 63;
  const int wave = tid >> 6;
  const int wm = wave & 1, wn = wave >> 1;
  const int gcol = ((lane & 7) ^ (lane >> 3)) << 3;  // element offset within K-slab
  char* ldsAc = (char*)ldsA;
  char* ldsBc = (char*)ldsB;
  const int mA = wm * 64 + (lane & 15);
  const int nB = wn * 64 + (lane & 15);
  const int kq = (lane >> 4) & 3;
  const int swz = lane & 7;
  for (int k0 = 0; k0 < KTOT; k0 += 64) {
    __syncthreads();  // previous compute done before overwriting LDS
#pragma unroll
    for (int c = 0; c < 4; ++c) {
      const int ldsRow = wave * 32 + c * 8;
      async_load16(aRow[c] + k0 + gcol, ldsAc + ldsRow * 128);
      async_load16(bRow[c] + k0 + gcol, ldsBc + ldsRow * 128);
    }
    __syncthreads();  // compiler inserts vmcnt(0) drain
#pragma unroll
    for (int ks = 0; ks < 2; ++ks) {
      bf16x8 aF[4], bF[4];
      const int u = ((((ks << 2) + kq) ^ swz) << 4);
#pragma unroll
      for (int i = 0; i < 4; ++i)
        aF[i] = *(const bf16x8*)(ldsAc + (mA + i * 16) * 128 + u);
#pragma unroll
      for (int j = 0; j < 4; ++j)
        bF[j] = *(const bf16x8*)(ldsBc + (nB + j * 16) * 128 + u);
#pragma unroll
      for (int i = 0; i < 4; ++i)
#pragma unroll
        for (int j = 0; j < 4; ++j)
          acc[i][j] = __builtin_amdgcn_mfma_f32_16x16x32_bf16(aF[i], bF[j], acc[i][j], 0, 0, 0);
    }
  }
}

// map linear tile id -> (game, row range); returns false if idle block
__device__ __forceinline__ bool seg_map(const int* __restrict__ off, int T,
                                        int& g, int& seg1, int& row0) {
  int base = 0;
  for (int gg = 0; gg < 8; ++gg) {
    const int s = off[gg], e = off[gg + 1];
    const int nt = (e - s + 127) >> 7;
    if (T < base + nt) { g = gg; seg1 = e; row0 = s + (T - base) * 128; return true; }
    base += nt;
  }
  return false;
}

// ------------- GEMM1: h1[p] = relu(sPerm[p] @ W1[g] + b1[g]), grouped -------------
__global__ __launch_bounds__(256) void k_gemm1(const unsigned short* __restrict__ sPerm,
                                               const unsigned short* __restrict__ W1T,
                                               const float* __restrict__ b1,
                                               const int* __restrict__ off,
                                               unsigned short* __restrict__ h1out) {
  __shared__ unsigned short ldsA[128 * 64];
  __shared__ unsigned short ldsB[128 * 64];
  int g, seg1, row0;
  if (!seg_map(off, blockIdx.x, g, seg1, row0)) return;
  const int col0 = blockIdx.y * 128;
  const int tid = threadIdx.x, lane = tid & 63, wave = tid >> 6;
  const unsigned short* aRow[4];
  const unsigned short* bRow[4];
#pragma unroll
  for (int c = 0; c < 4; ++c) {
    int r = row0 + wave * 32 + c * 8 + (lane >> 3);
    if (r > seg1 - 1) r = seg1 - 1;
    aRow[c] = sPerm + (size_t)r * D_IN;
    const int nr = col0 + wave * 32 + c * 8 + (lane >> 3);
    bRow[c] = W1T + (size_t)g * H1 * D_IN + (size_t)nr * D_IN;
  }
  f32x4 acc[4][4] = {};
  gemm_mfma_core(aRow, bRow, ldsA, ldsB, D_IN, tid, acc);
  const int wm = wave & 1, wn = wave >> 1;
  const float* bg = b1 + g * H1;
#pragma unroll
  for (int j = 0; j < 4; ++j) {
    const int n = col0 + wn * 64 + j * 16 + (lane & 15);
    const float bj = bg[n];
#pragma unroll
    for (int i = 0; i < 4; ++i) {
      const int rbase = row0 + wm * 64 + i * 16 + ((lane >> 4) << 2);
#pragma unroll
      for (int r = 0; r < 4; ++r) {
        const int p = rbase + r;
        if (p < seg1) {
          float v = acc[i][j][r] + bj;
          v = fmaxf(v, 0.0f);
          h1out[(size_t)p * H1 + n] = f2bf(v);
        }
      }
    }
  }
}

// ------------- GEMM2: h_f = relu(h1 @ W2 + b2) -------------
__global__ __launch_bounds__(256) void k_gemm2(const unsigned short* __restrict__ h1in,
                                               const unsigned short* __restrict__ W2T,
                                               const float* __restrict__ b2,
                                               unsigned short* __restrict__ hfout) {
  __shared__ unsigned short ldsA[128 * 64];
  __shared__ unsigned short ldsB[128 * 64];
  const int row0 = blockIdx.x * 128, col0 = blockIdx.y * 128;
  const int tid = threadIdx.x, lane = tid & 63, wave = tid >> 6;
  const unsigned short* aRow[4];
  const unsigned short* bRow[4];
#pragma unroll
  for (int c = 0; c < 4; ++c) {
    const int r = row0 + wave * 32 + c * 8 + (lane >> 3);
    aRow[c] = h1in + (size_t)r * H1;
    const int nr = col0 + wave * 32 + c * 8 + (lane >> 3);
    bRow[c] = W2T + (size_t)nr * H1;
  }
  f32x4 acc[4][4] = {};
  gemm_mfma_core(aRow, bRow, ldsA, ldsB, H1, tid, acc);
  const int wm = wave & 1, wn = wave >> 1;
#pragma unroll
  for (int j = 0; j < 4; ++j) {
    const int n = col0 + wn * 64 + j * 16 + (lane & 15);
    const float bj = b2[n];
#pragma unroll
    for (int i = 0; i < 4; ++i) {
      const int rbase = row0 + wm * 64 + i * 16 + ((lane >> 4) << 2);
#pragma unroll
      for (int r = 0; r < 4; ++r) {
        float v = acc[i][j][r] + bj;
        v = fmaxf(v, 0.0f);
        hfout[(size_t)(rbase + r) * H2 + n] = f2bf(v);
      }
    }
  }
}

// ------------- GEMM3: out[perm[q]] = tanh(h_f[perm[q]] @ W3[g] + b3[g]), grouped -------------
__global__ __launch_bounds__(256) void k_gemm3(const unsigned short* __restrict__ hf,
                                               const unsigned short* __restrict__ W3T,
                                               const float* __restrict__ b3,
                                               const int* __restrict__ off,
                                               const int* __restrict__ perm,
                                               float* __restrict__ outp) {
  __shared__ unsigned short ldsA[128 * 64];
  __shared__ unsigned short ldsB[128 * 64];
  int g, seg1, row0;
  if (!seg_map(off, blockIdx.x, g, seg1, row0)) return;
  const int tid = threadIdx.x, lane = tid & 63, wave = tid >> 6;
  const unsigned short* aRow[4];
  const unsigned short* bRow[4];
#pragma unroll
  for (int c = 0; c < 4; ++c) {
    int q = row0 + wave * 32 + c * 8 + (lane >> 3);
    if (q > seg1 - 1) q = seg1 - 1;
    const int r = perm[q];
    aRow[c] = hf + (size_t)r * H2;
    const int nr = wave * 32 + c * 8 + (lane >> 3);  // BN = A_DIM = 128, col0 = 0
    bRow[c] = W3T + (size_t)g * A_DIM * H2 + (size_t)nr * H2;
  }
  f32x4 acc[4][4] = {};
  gemm_mfma_core(aRow, bRow, ldsA, ldsB, H2, tid, acc);
  const int wm = wave & 1, wn = wave >> 1;
  const float* bg = b3 + g * A_DIM;
#pragma unroll
  for (int j = 0; j < 4; ++j) {
    const int n = wn * 64 + j * 16 + (lane & 15);
    const float bj = bg[n];
#pragma unroll
    for (int i = 0; i < 4; ++i) {
      const int qbase = row0 + wm * 64 + i * 16 + ((lane >> 4) << 2);
#pragma unroll
      for (int r = 0; r < 4; ++r) {
        const int q = qbase + r;
        if (q < seg1) {
          const int orow = perm[q];
          outp[(size_t)orow * A_DIM + n] = tanhf(acc[i][j][r] + bj);
        }
      }
    }
  }
}

extern "C" void kernel_launch(void* const* d_in, const int* in_sizes, int n_in,
                              void* d_out, int out_size, void* d_ws, size_t ws_size,
                              hipStream_t stream) {
  (void)in_sizes; (void)n_in; (void)out_size; (void)ws_size;
  const float* state = (const float*)d_in[0];
  const int*   idx   = (const int*)d_in[1];
  const float* W1    = (const float*)d_in[2];
  const float* b1    = (const float*)d_in[3];
  const float* W2    = (const float*)d_in[4];
  const float* b2    = (const float*)d_in[5];
  const float* W3    = (const float*)d_in[6];
  const float* b3    = (const float*)d_in[7];
  float* outp = (float*)d_out;
  char* ws = (char*)d_ws;
  int* off  = (int*)(ws + WS_OFF);
  int* perm = (int*)(ws + WS_PERM);
  unsigned short* sPerm = (unsigned short*)(ws + WS_SPERM);
  unsigned short* W1T   = (unsigned short*)(ws + WS_W1T);
  unsigned short* W2T   = (unsigned short*)(ws + WS_W2T);
  unsigned short* W3T   = (unsigned short*)(ws + WS_W3T);
  unsigned short* h1    = (unsigned short*)(ws + WS_H1);
  unsigned short* hf    = (unsigned short*)(ws + WS_HF);  // aliases sPerm/W1T

  hipLaunchKernelGGL(k_sort, dim3(1), dim3(1024), 0, stream, idx, perm, off);
  hipLaunchKernelGGL(k_transpose, dim3(H1 / 64, D_IN / 64, G_GAMES), dim3(256), 0, stream,
                     W1, W1T, D_IN, H1);
  hipLaunchKernelGGL(k_transpose, dim3(H2 / 64, H1 / 64, 1), dim3(256), 0, stream,
                     W2, W2T, H1, H2);
  hipLaunchKernelGGL(k_transpose, dim3(A_DIM / 64, H2 / 64, G_GAMES), dim3(256), 0, stream,
                     W3, W3T, H2, A_DIM);
  hipLaunchKernelGGL(k_gather, dim3(B_ROWS / 2), dim3(256), 0, stream, state, perm, sPerm);
  hipLaunchKernelGGL(k_gemm1, dim3(72, 8), dim3(256), 0, stream, sPerm, W1T, b1, off, h1);
  hipLaunchKernelGGL(k_gemm2, dim3(64, 8), dim3(256), 0, stream, h1, W2T, b2, hf);
  hipLaunchKernelGGL(k_gemm3, dim3(72, 1), dim3(256), 0, stream, hf, W3T, b3, off, perm, outp);
}

// Round 2
// 177.283 us; speedup vs baseline: 1.1574x; 1.1574x over previous
//
#include <hip/hip_runtime.h>
#include <math.h>

#define G_GAMES 8
#define D_IN 512
#define H1 1024
#define H2 1024
#define A_DIM 128
#define B_ROWS 8192

typedef short bf16x8 __attribute__((ext_vector_type(8)));
typedef float f32x4 __attribute__((ext_vector_type(4)));

// ---------- workspace layout (bytes) ----------
#define WS_OFF   0u                                   // 16 ints
#define WS_PERM  256u                                 // 8192 ints
#define WS_SPERM 33280u                               // B*D_IN bf16 = 8388608
#define WS_W1T   (WS_SPERM + B_ROWS*D_IN*2u)          // G*H1*D_IN bf16
#define WS_W2T   (WS_W1T + G_GAMES*D_IN*H1*2u)        // H2*H1 bf16
#define WS_W3T   (WS_W2T + (unsigned)H1*H2*2u)        // G*A*H2 bf16
#define WS_H1    (WS_W3T + G_GAMES*H2*A_DIM*2u)       // B*H1 bf16
#define WS_HF    WS_SPERM                             // aliases sPerm+W1T (dead after gemm1)
// total required: 37,782,016 bytes

__device__ __forceinline__ unsigned short f2bf(float x) {
  union { float f; unsigned int u; } v; v.f = x;
  unsigned int r = v.u + 0x7fffu + ((v.u >> 16) & 1u);
  return (unsigned short)(r >> 16);
}

__device__ __forceinline__ void async_load16(const void* gptr, void* ldsptr) {
  __builtin_amdgcn_global_load_lds(
      (const __attribute__((address_space(1))) unsigned int*)gptr,
      (__attribute__((address_space(3))) unsigned int*)ldsptr,
      16, 0, 0);
}

// ---------------- stable counting sort of idx (B=8192, G=8) ----------------
// wave-shuffle scans: 3 barriers total (vs 20 in the Hillis-Steele version)
__global__ __launch_bounds__(1024) void k_sort(const int* __restrict__ idx,
                                               int* __restrict__ perm,
                                               int* __restrict__ off) {
  __shared__ int wtot[16][9];   // per-wave totals per game
  __shared__ int wbase[16][9];  // exclusive scan of wave totals per game
  __shared__ int offs[9];
  const int t = threadIdx.x;
  const int lane = t & 63, wave = t >> 6;
  int my[8];
  {
    const int4 a = *(const int4*)(idx + t * 8);
    const int4 b = *(const int4*)(idx + t * 8 + 4);
    my[0] = a.x; my[1] = a.y; my[2] = a.z; my[3] = a.w;
    my[4] = b.x; my[5] = b.y; my[6] = b.z; my[7] = b.w;
  }
  int local[8] = {0,0,0,0,0,0,0,0};
#pragma unroll
  for (int i = 0; i < 8; ++i) local[my[i]]++;
  // intra-wave inclusive scan per game
  int incl[8];
#pragma unroll
  for (int g = 0; g < 8; ++g) {
    int v = local[g];
#pragma unroll
    for (int d = 1; d < 64; d <<= 1) {
      const int n = __shfl_up(v, d);
      if (lane >= d) v += n;
    }
    incl[g] = v;
  }
  if (lane == 63) {
#pragma unroll
    for (int g = 0; g < 8; ++g) wtot[wave][g] = incl[g];
  }
  __syncthreads();
  if (t < 8) {  // thread t owns game t: scan 16 wave totals
    int s = 0;
#pragma unroll
    for (int w = 0; w < 16; ++w) { wbase[w][t] = s; s += wtot[w][t]; }
    wtot[0][t] = s;  // reuse as game total
  }
  __syncthreads();
  if (t == 0) {
    int s = 0;
#pragma unroll
    for (int g = 0; g < 8; ++g) { offs[g] = s; off[g] = s; s += wtot[0][g]; }
    offs[8] = s; off[8] = s;
  }
  __syncthreads();
  int start[8];
#pragma unroll
  for (int g = 0; g < 8; ++g)
    start[g] = offs[g] + wbase[wave][g] + (incl[g] - local[g]);
#pragma unroll
  for (int i = 0; i < 8; ++i) {
    const int g = my[i];
    perm[start[g]++] = t * 8 + i;
  }
}

// ------------- merged prep: 3 weight transposes + state gather (one launch) -------------
__device__ __forceinline__ void trans_tile(const float* __restrict__ in,
                                           unsigned short* __restrict__ out,
                                           int R, int C, int xt, int yt, int z) {
  in  += (size_t)z * R * C;
  out += (size_t)z * R * C;
  __shared__ float tile[64][65];
  const int c0 = xt * 64, r0 = yt * 64;
  const int tx = threadIdx.x & 63, ty = threadIdx.x >> 6;
#pragma unroll
  for (int rr = ty; rr < 64; rr += 4)
    tile[rr][tx] = in[(size_t)(r0 + rr) * C + c0 + tx];
  __syncthreads();
#pragma unroll
  for (int cc = ty; cc < 64; cc += 4)
    out[(size_t)(c0 + cc) * R + r0 + tx] = f2bf(tile[tx][cc]);
}

// blocks: [0,1024) W1, [1024,1280) W2, [1280,1536) W3, [1536,5632) gather
__global__ __launch_bounds__(256) void k_prep(const float* __restrict__ W1,
                                              const float* __restrict__ W2,
                                              const float* __restrict__ W3,
                                              const float* __restrict__ state,
                                              const int* __restrict__ perm,
                                              unsigned short* __restrict__ W1T,
                                              unsigned short* __restrict__ W2T,
                                              unsigned short* __restrict__ W3T,
                                              unsigned short* __restrict__ sPerm) {
  const int b = blockIdx.x;
  if (b < 1024) {           // W1: per game 16 x-tiles (C=H1) x 8 y-tiles (R=D_IN)
    const int z = b >> 7, r = b & 127;
    trans_tile(W1, W1T, D_IN, H1, r & 15, r >> 4, z);
  } else if (b < 1280) {    // W2: 16 x 16 tiles
    const int r = b - 1024;
    trans_tile(W2, W2T, H1, H2, r & 15, r >> 4, 0);
  } else if (b < 1536) {    // W3: per game 2 x-tiles (C=A) x 16 y-tiles (R=H2)
    const int r = (b - 1280) & 31, z = (b - 1280) >> 5;
    trans_tile(W3, W3T, H2, A_DIM, r & 1, r >> 1, z);
  } else {                  // gather: 4096 blocks, 2 rows each
    const int bb = b - 1536;
    const int p = bb * 2 + (threadIdx.x >> 7);
    const int c = (threadIdx.x & 127) << 2;
    const int src = perm[p];
    const float4 v = *(const float4*)(state + (size_t)src * D_IN + c);
    ushort4 o;
    o.x = f2bf(v.x); o.y = f2bf(v.y); o.z = f2bf(v.z); o.w = f2bf(v.w);
    *(ushort4*)(sPerm + (size_t)p * D_IN + c) = o;
  }
}

// ------------- shared MFMA GEMM core: 128x128 tile, BK=64, 4 waves 2x2, 4x4 accs -------------
// LDS layout: per row 8x16B units, physical unit = logical ^ (row&7)  (<=2-way bank aliasing)
__device__ __forceinline__ void gemm_mfma_core(const unsigned short* const* aRow,
                                               const unsigned short* const* bRow,
                                               unsigned short* ldsA, unsigned short* ldsB,
                                               int KTOT, int tid, f32x4 acc[4][4]) {
  const int lane = tid & 63;
  const int wave = tid >> 6;
  const int wm = wave & 1, wn = wave >> 1;
  const int gcol = ((lane & 7) ^ (lane >> 3)) << 3;
  char* ldsAc = (char*)ldsA;
  char* ldsBc = (char*)ldsB;
  const int mA = wm * 64 + (lane & 15);
  const int nB = wn * 64 + (lane & 15);
  const int kq = (lane >> 4) & 3;
  const int swz = lane & 7;
  for (int k0 = 0; k0 < KTOT; k0 += 64) {
    __syncthreads();
#pragma unroll
    for (int c = 0; c < 4; ++c) {
      const int ldsRow = wave * 32 + c * 8;
      async_load16(aRow[c] + k0 + gcol, ldsAc + ldsRow * 128);
      async_load16(bRow[c] + k0 + gcol, ldsBc + ldsRow * 128);
    }
    __syncthreads();
#pragma unroll
    for (int ks = 0; ks < 2; ++ks) {
      bf16x8 aF[4], bF[4];
      const int u = ((((ks << 2) + kq) ^ swz) << 4);
#pragma unroll
      for (int i = 0; i < 4; ++i)
        aF[i] = *(const bf16x8*)(ldsAc + (mA + i * 16) * 128 + u);
#pragma unroll
      for (int j = 0; j < 4; ++j)
        bF[j] = *(const bf16x8*)(ldsBc + (nB + j * 16) * 128 + u);
#pragma unroll
      for (int i = 0; i < 4; ++i)
#pragma unroll
        for (int j = 0; j < 4; ++j)
          acc[i][j] = __builtin_amdgcn_mfma_f32_16x16x32_bf16(aF[i], bF[j], acc[i][j], 0, 0, 0);
    }
  }
}

__device__ __forceinline__ bool seg_map(const int* __restrict__ off, int T,
                                        int& g, int& seg1, int& row0) {
  int base = 0;
  for (int gg = 0; gg < 8; ++gg) {
    const int s = off[gg], e = off[gg + 1];
    const int nt = (e - s + 127) >> 7;
    if (T < base + nt) { g = gg; seg1 = e; row0 = s + (T - base) * 128; return true; }
    base += nt;
  }
  return false;
}

__device__ __forceinline__ bool seg_map32(const int* __restrict__ off, int T,
                                          int& g, int& seg1, int& row0) {
  int base = 0;
  for (int gg = 0; gg < 8; ++gg) {
    const int s = off[gg], e = off[gg + 1];
    const int nt = (e - s + 31) >> 5;
    if (T < base + nt) { g = gg; seg1 = e; row0 = s + (T - base) * 32; return true; }
    base += nt;
  }
  return false;
}

// ------------- GEMM1: h1[p] = relu(sPerm[p] @ W1[g] + b1[g]), grouped -------------
__global__ __launch_bounds__(256) void k_gemm1(const unsigned short* __restrict__ sPerm,
                                               const unsigned short* __restrict__ W1T,
                                               const float* __restrict__ b1,
                                               const int* __restrict__ off,
                                               unsigned short* __restrict__ h1out) {
  __shared__ unsigned short ldsA[128 * 64];
  __shared__ unsigned short ldsB[128 * 64];
  int g, seg1, row0;
  if (!seg_map(off, blockIdx.x, g, seg1, row0)) return;
  const int col0 = blockIdx.y * 128;
  const int tid = threadIdx.x, lane = tid & 63, wave = tid >> 6;
  const unsigned short* aRow[4];
  const unsigned short* bRow[4];
#pragma unroll
  for (int c = 0; c < 4; ++c) {
    int r = row0 + wave * 32 + c * 8 + (lane >> 3);
    if (r > seg1 - 1) r = seg1 - 1;
    aRow[c] = sPerm + (size_t)r * D_IN;
    const int nr = col0 + wave * 32 + c * 8 + (lane >> 3);
    bRow[c] = W1T + (size_t)g * H1 * D_IN + (size_t)nr * D_IN;
  }
  f32x4 acc[4][4] = {};
  gemm_mfma_core(aRow, bRow, ldsA, ldsB, D_IN, tid, acc);
  const int wm = wave & 1, wn = wave >> 1;
  const float* bg = b1 + g * H1;
#pragma unroll
  for (int j = 0; j < 4; ++j) {
    const int n = col0 + wn * 64 + j * 16 + (lane & 15);
    const float bj = bg[n];
#pragma unroll
    for (int i = 0; i < 4; ++i) {
      const int rbase = row0 + wm * 64 + i * 16 + ((lane >> 4) << 2);
#pragma unroll
      for (int r = 0; r < 4; ++r) {
        const int p = rbase + r;
        if (p < seg1) {
          float v = acc[i][j][r] + bj;
          v = fmaxf(v, 0.0f);
          h1out[(size_t)p * H1 + n] = f2bf(v);
        }
      }
    }
  }
}

// ------------- GEMM2: h_f = relu(h1 @ W2 + b2) -------------
__global__ __launch_bounds__(256) void k_gemm2(const unsigned short* __restrict__ h1in,
                                               const unsigned short* __restrict__ W2T,
                                               const float* __restrict__ b2,
                                               unsigned short* __restrict__ hfout) {
  __shared__ unsigned short ldsA[128 * 64];
  __shared__ unsigned short ldsB[128 * 64];
  const int row0 = blockIdx.x * 128, col0 = blockIdx.y * 128;
  const int tid = threadIdx.x, lane = tid & 63, wave = tid >> 6;
  const unsigned short* aRow[4];
  const unsigned short* bRow[4];
#pragma unroll
  for (int c = 0; c < 4; ++c) {
    const int r = row0 + wave * 32 + c * 8 + (lane >> 3);
    aRow[c] = h1in + (size_t)r * H1;
    const int nr = col0 + wave * 32 + c * 8 + (lane >> 3);
    bRow[c] = W2T + (size_t)nr * H1;
  }
  f32x4 acc[4][4] = {};
  gemm_mfma_core(aRow, bRow, ldsA, ldsB, H1, tid, acc);
  const int wm = wave & 1, wn = wave >> 1;
#pragma unroll
  for (int j = 0; j < 4; ++j) {
    const int n = col0 + wn * 64 + j * 16 + (lane & 15);
    const float bj = b2[n];
#pragma unroll
    for (int i = 0; i < 4; ++i) {
      const int rbase = row0 + wm * 64 + i * 16 + ((lane >> 4) << 2);
#pragma unroll
      for (int r = 0; r < 4; ++r) {
        float v = acc[i][j][r] + bj;
        v = fmaxf(v, 0.0f);
        hfout[(size_t)(rbase + r) * H2 + n] = f2bf(v);
      }
    }
  }
}

// ------------- GEMM3: 32-row grouped tiles for occupancy (264 blocks) -------------
// out[perm[q]] = tanh(hf[perm[q]] @ W3[g] + b3[g])
__global__ __launch_bounds__(256) void k_gemm3(const unsigned short* __restrict__ hf,
                                               const unsigned short* __restrict__ W3T,
                                               const float* __restrict__ b3,
                                               const int* __restrict__ off,
                                               const int* __restrict__ perm,
                                               float* __restrict__ outp) {
  __shared__ unsigned short ldsA[32 * 64];
  __shared__ unsigned short ldsB[128 * 64];
  int g, seg1, row0;
  if (!seg_map32(off, blockIdx.x, g, seg1, row0)) return;
  const int tid = threadIdx.x, lane = tid & 63, wave = tid >> 6;
  const int wm = wave & 1, wn = wave >> 1;
  const int gcol = ((lane & 7) ^ (lane >> 3)) << 3;
  // A: one row per thread (32 rows x 8 lanes each)
  int q = row0 + wave * 8 + (lane >> 3);
  if (q > seg1 - 1) q = seg1 - 1;
  const unsigned short* aPtr = hf + (size_t)perm[q] * H2;
  const unsigned short* bRow[4];
#pragma unroll
  for (int c = 0; c < 4; ++c) {
    const int nr = wave * 32 + c * 8 + (lane >> 3);
    bRow[c] = W3T + (size_t)g * A_DIM * H2 + (size_t)nr * H2;
  }
  char* ldsAc = (char*)ldsA;
  char* ldsBc = (char*)ldsB;
  const int mA = wm * 16 + (lane & 15);
  const int nB = wn * 64 + (lane & 15);
  const int kq = (lane >> 4) & 3;
  const int swz = lane & 7;
  f32x4 acc[4] = {};
  for (int k0 = 0; k0 < H2; k0 += 64) {
    __syncthreads();
    async_load16(aPtr + k0 + gcol, ldsAc + (wave * 8) * 128);
#pragma unroll
    for (int c = 0; c < 4; ++c)
      async_load16(bRow[c] + k0 + gcol, ldsBc + (wave * 32 + c * 8) * 128);
    __syncthreads();
#pragma unroll
    for (int ks = 0; ks < 2; ++ks) {
      const int u = ((((ks << 2) + kq) ^ swz) << 4);
      const bf16x8 aF = *(const bf16x8*)(ldsAc + mA * 128 + u);
      bf16x8 bF[4];
#pragma unroll
      for (int j = 0; j < 4; ++j)
        bF[j] = *(const bf16x8*)(ldsBc + (nB + j * 16) * 128 + u);
#pragma unroll
      for (int j = 0; j < 4; ++j)
        acc[j] = __builtin_amdgcn_mfma_f32_16x16x32_bf16(aF, bF[j], acc[j], 0, 0, 0);
    }
  }
  const float* bg = b3 + g * A_DIM;
#pragma unroll
  for (int j = 0; j < 4; ++j) {
    const int n = wn * 64 + j * 16 + (lane & 15);
    const float bj = bg[n];
    const int qbase = row0 + wm * 16 + ((lane >> 4) << 2);
#pragma unroll
    for (int r = 0; r < 4; ++r) {
      const int q2 = qbase + r;
      if (q2 < seg1)
        outp[(size_t)perm[q2] * A_DIM + n] = tanhf(acc[j][r] + bj);
    }
  }
}

extern "C" void kernel_launch(void* const* d_in, const int* in_sizes, int n_in,
                              void* d_out, int out_size, void* d_ws, size_t ws_size,
                              hipStream_t stream) {
  (void)in_sizes; (void)n_in; (void)out_size; (void)ws_size;
  const float* state = (const float*)d_in[0];
  const int*   idx   = (const int*)d_in[1];
  const float* W1    = (const float*)d_in[2];
  const float* b1    = (const float*)d_in[3];
  const float* W2    = (const float*)d_in[4];
  const float* b2    = (const float*)d_in[5];
  const float* W3    = (const float*)d_in[6];
  const float* b3    = (const float*)d_in[7];
  float* outp = (float*)d_out;
  char* ws = (char*)d_ws;
  int* off  = (int*)(ws + WS_OFF);
  int* perm = (int*)(ws + WS_PERM);
  unsigned short* sPerm = (unsigned short*)(ws + WS_SPERM);
  unsigned short* W1T   = (unsigned short*)(ws + WS_W1T);
  unsigned short* W2T   = (unsigned short*)(ws + WS_W2T);
  unsigned short* W3T   = (unsigned short*)(ws + WS_W3T);
  unsigned short* h1    = (unsigned short*)(ws + WS_H1);
  unsigned short* hf    = (unsigned short*)(ws + WS_HF);

  hipLaunchKernelGGL(k_sort, dim3(1), dim3(1024), 0, stream, idx, perm, off);
  hipLaunchKernelGGL(k_prep, dim3(1536 + B_ROWS / 2), dim3(256), 0, stream,
                     W1, W2, W3, state, perm, W1T, W2T, W3T, sPerm);
  hipLaunchKernelGGL(k_gemm1, dim3(72, 8), dim3(256), 0, stream, sPerm, W1T, b1, off, h1);
  hipLaunchKernelGGL(k_gemm2, dim3(64, 8), dim3(256), 0, stream, h1, W2T, b2, hf);
  hipLaunchKernelGGL(k_gemm3, dim3(264), dim3(256), 0, stream, hf, W3T, b3, off, perm, outp);
}

// Round 3
// 172.285 us; speedup vs baseline: 1.1909x; 1.0290x over previous
//
#include <hip/hip_runtime.h>
#include <math.h>

#define G_GAMES 8
#define D_IN 512
#define H1 1024
#define H2 1024
#define A_DIM 128
#define B_ROWS 8192

typedef short bf16x8 __attribute__((ext_vector_type(8)));
typedef float f32x4 __attribute__((ext_vector_type(4)));

// ---------- workspace layout (bytes) ----------
#define WS_OFF   0u
#define WS_PERM  256u
#define WS_SPERM 33280u                               // B*D_IN bf16
#define WS_W1T   (WS_SPERM + B_ROWS*D_IN*2u)          // G*H1*D_IN bf16
#define WS_W2T   (WS_W1T + G_GAMES*D_IN*H1*2u)        // H2*H1 bf16
#define WS_W3T   (WS_W2T + (unsigned)H1*H2*2u)        // G*A*H2 bf16
#define WS_H1    (WS_W3T + G_GAMES*H2*A_DIM*2u)       // B*H1 bf16
#define WS_HF    WS_SPERM                             // aliases sPerm (dead after gemm1)

__device__ __forceinline__ unsigned short f2bf(float x) {
  union { float f; unsigned int u; } v; v.f = x;
  unsigned int r = v.u + 0x7fffu + ((v.u >> 16) & 1u);
  return (unsigned short)(r >> 16);
}

__device__ __forceinline__ void async_load16(const void* gptr, void* ldsptr) {
  __builtin_amdgcn_global_load_lds(
      (const __attribute__((address_space(1))) unsigned int*)gptr,
      (__attribute__((address_space(3))) unsigned int*)ldsptr,
      16, 0, 0);
}

// ---------------- stable counting sort (256 threads, 32 elems each) ----------------
__device__ void sort_256(const int* __restrict__ idx, int* __restrict__ perm,
                         int* __restrict__ off) {
  __shared__ int wtot[4][9];
  __shared__ int wbase[4][9];
  __shared__ int offs[9];
  const int t = threadIdx.x, lane = t & 63, wave = t >> 6;
  int my[32];
#pragma unroll
  for (int i = 0; i < 8; ++i) {
    const int4 a = *(const int4*)(idx + t * 32 + i * 4);
    my[i*4+0] = a.x; my[i*4+1] = a.y; my[i*4+2] = a.z; my[i*4+3] = a.w;
  }
  int local[8] = {0,0,0,0,0,0,0,0};
#pragma unroll
  for (int i = 0; i < 32; ++i) local[my[i]]++;
  int incl[8];
#pragma unroll
  for (int g = 0; g < 8; ++g) {
    int v = local[g];
#pragma unroll
    for (int d = 1; d < 64; d <<= 1) {
      const int n = __shfl_up(v, d);
      if (lane >= d) v += n;
    }
    incl[g] = v;
  }
  if (lane == 63) {
#pragma unroll
    for (int g = 0; g < 8; ++g) wtot[wave][g] = incl[g];
  }
  __syncthreads();
  if (t < 8) {
    int s = 0;
#pragma unroll
    for (int w = 0; w < 4; ++w) { wbase[w][t] = s; s += wtot[w][t]; }
    wtot[0][t] = s;
  }
  __syncthreads();
  if (t == 0) {
    int s = 0;
#pragma unroll
    for (int g = 0; g < 8; ++g) { offs[g] = s; off[g] = s; s += wtot[0][g]; }
    offs[8] = s; off[8] = s;
  }
  __syncthreads();
  int start[8];
#pragma unroll
  for (int g = 0; g < 8; ++g)
    start[g] = offs[g] + wbase[wave][g] + (incl[g] - local[g]);
#pragma unroll
  for (int i = 0; i < 32; ++i) {
    const int g = my[i];
    perm[start[g]++] = t * 32 + i;
  }
}

// ------------- fp32 [R][C] -> bf16 [C][R] transpose tile (64x64) -------------
__device__ void trans_tile(const float* __restrict__ in,
                           unsigned short* __restrict__ out,
                           int R, int C, int xt, int yt, int z) {
  in  += (size_t)z * R * C;
  out += (size_t)z * R * C;
  __shared__ float tile[64][65];
  const int c0 = xt * 64, r0 = yt * 64;
  const int tx = threadIdx.x & 63, ty = threadIdx.x >> 6;
#pragma unroll
  for (int rr = ty; rr < 64; rr += 4)
    tile[rr][tx] = in[(size_t)(r0 + rr) * C + c0 + tx];
  __syncthreads();
#pragma unroll
  for (int cc = ty; cc < 64; cc += 4)
    out[(size_t)(c0 + cc) * R + r0 + tx] = f2bf(tile[tx][cc]);
}

// blocks: [0,1024) W1, [1024,1280) W2, [1280,1536) W3, 1536 = sort
__global__ __launch_bounds__(256) void k_pre1(const float* __restrict__ W1,
                                              const float* __restrict__ W2,
                                              const float* __restrict__ W3,
                                              const int* __restrict__ idx,
                                              unsigned short* __restrict__ W1T,
                                              unsigned short* __restrict__ W2T,
                                              unsigned short* __restrict__ W3T,
                                              int* __restrict__ perm,
                                              int* __restrict__ off) {
  const int b = blockIdx.x;
  if (b < 1024) {
    const int z = b >> 7, r = b & 127;
    trans_tile(W1, W1T, D_IN, H1, r & 15, r >> 4, z);
  } else if (b < 1280) {
    const int r = b - 1024;
    trans_tile(W2, W2T, H1, H2, r & 15, r >> 4, 0);
  } else if (b < 1536) {
    const int r = (b - 1280) & 31, z = (b - 1280) >> 5;
    trans_tile(W3, W3T, H2, A_DIM, r & 1, r >> 1, z);
  } else {
    sort_256(idx, perm, off);
  }
}

// ------------- gather state rows by perm, fp32 -> bf16 -------------
__global__ __launch_bounds__(256) void k_gather(const float* __restrict__ state,
                                                const int* __restrict__ perm,
                                                unsigned short* __restrict__ sPerm) {
  const int p = blockIdx.x * 2 + (threadIdx.x >> 7);
  const int c = (threadIdx.x & 127) << 2;
  const int src = perm[p];
  const float4 v = *(const float4*)(state + (size_t)src * D_IN + c);
  ushort4 o;
  o.x = f2bf(v.x); o.y = f2bf(v.y); o.z = f2bf(v.z); o.w = f2bf(v.w);
  *(ushort4*)(sPerm + (size_t)p * D_IN + c) = o;
}

// ------------- MFMA core: 128x128 tile, BK=128, 4 waves 2x2, 4x4 accs -------------
// LDS: 128 rows x 256B; physical 16B-unit = logical ^ (row&15)  (2-way aliasing = free)
// aP/bP: 8 fully-baked per-lane pointers (row + XOR'd unit offset included)
__device__ __forceinline__ void gemm_core128(const unsigned short* const* aP,
                                             const unsigned short* const* bP,
                                             char* A, char* Bc,
                                             int KTOT, int tid, f32x4 acc[4][4]) {
  const int lane = tid & 63, wave = tid >> 6;
  const int wm = wave & 1, wn = wave >> 1;
  const int mA = wm * 64 + (lane & 15);
  const int nB = wn * 64 + (lane & 15);
  const int quad = lane >> 4;
  const int sw = lane & 15;
  for (int k0 = 0; k0 < KTOT; k0 += 128) {
    __syncthreads();
#pragma unroll
    for (int c = 0; c < 8; ++c) {
      const int rbase = wave * 32 + c * 4;
      async_load16(aP[c] + k0, A + rbase * 256);
      async_load16(bP[c] + k0, Bc + rbase * 256);
    }
    __syncthreads();
#pragma unroll
    for (int ks = 0; ks < 4; ++ks) {
      const int u = (((ks * 4 + quad) ^ sw) << 4);
      bf16x8 aF[4], bF[4];
#pragma unroll
      for (int i = 0; i < 4; ++i) {
        aF[i] = *(const bf16x8*)(A + (mA + i * 16) * 256 + u);
        bF[i] = *(const bf16x8*)(Bc + (nB + i * 16) * 256 + u);
      }
#pragma unroll
      for (int i = 0; i < 4; ++i)
#pragma unroll
        for (int j = 0; j < 4; ++j)
          acc[i][j] = __builtin_amdgcn_mfma_f32_16x16x32_bf16(aF[i], bF[j], acc[i][j], 0, 0, 0);
    }
  }
}

__device__ __forceinline__ bool seg_map(const int* __restrict__ off, int T,
                                        int& g, int& seg1, int& row0) {
  int base = 0;
  for (int gg = 0; gg < 8; ++gg) {
    const int s = off[gg], e = off[gg + 1];
    const int nt = (e - s + 127) >> 7;
    if (T < base + nt) { g = gg; seg1 = e; row0 = s + (T - base) * 128; return true; }
    base += nt;
  }
  return false;
}

__device__ __forceinline__ bool seg_map32(const int* __restrict__ off, int T,
                                          int& g, int& seg1, int& row0) {
  int base = 0;
  for (int gg = 0; gg < 8; ++gg) {
    const int s = off[gg], e = off[gg + 1];
    const int nt = (e - s + 31) >> 5;
    if (T < base + nt) { g = gg; seg1 = e; row0 = s + (T - base) * 32; return true; }
    base += nt;
  }
  return false;
}

// ------------- GEMM1: h1[p] = relu(sPerm[p] @ W1[g] + b1[g]), grouped -------------
__global__ __launch_bounds__(256) void k_gemm1(const unsigned short* __restrict__ sPerm,
                                               const unsigned short* __restrict__ W1T,
                                               const float* __restrict__ b1,
                                               const int* __restrict__ off,
                                               unsigned short* __restrict__ h1out) {
  __shared__ unsigned short ldsA[128 * 128];
  __shared__ unsigned short ldsB[128 * 128];
  int g, seg1, row0;
  if (!seg_map(off, blockIdx.x, g, seg1, row0)) return;
  const int col0 = blockIdx.y * 128;
  const int tid = threadIdx.x, lane = tid & 63, wave = tid >> 6;
  const int quad = lane >> 4, sw = lane & 15;
  const unsigned short* aP[8];
  const unsigned short* bP[8];
#pragma unroll
  for (int c = 0; c < 8; ++c) {
    const int rl = wave * 32 + c * 4 + quad;
    const int srcoff = ((sw ^ (rl & 15)) << 3);
    int p = row0 + rl;
    if (p > seg1 - 1) p = seg1 - 1;
    aP[c] = sPerm + (size_t)p * D_IN + srcoff;
    bP[c] = W1T + (size_t)g * H1 * D_IN + (size_t)(col0 + rl) * D_IN + srcoff;
  }
  f32x4 acc[4][4] = {};
  gemm_core128(aP, bP, (char*)ldsA, (char*)ldsB, D_IN, tid, acc);
  const int wm = wave & 1, wn = wave >> 1;
  const float* bg = b1 + g * H1;
#pragma unroll
  for (int j = 0; j < 4; ++j) {
    const int n = col0 + wn * 64 + j * 16 + sw;
    const float bj = bg[n];
#pragma unroll
    for (int i = 0; i < 4; ++i) {
      const int rbase = row0 + wm * 64 + i * 16 + (quad << 2);
#pragma unroll
      for (int r = 0; r < 4; ++r) {
        const int p = rbase + r;
        if (p < seg1) {
          float v = acc[i][j][r] + bj;
          v = fmaxf(v, 0.0f);
          h1out[(size_t)p * H1 + n] = f2bf(v);
        }
      }
    }
  }
}

// ------------- GEMM2: h_f = relu(h1 @ W2 + b2) -------------
__global__ __launch_bounds__(256) void k_gemm2(const unsigned short* __restrict__ h1in,
                                               const unsigned short* __restrict__ W2T,
                                               const float* __restrict__ b2,
                                               unsigned short* __restrict__ hfout) {
  __shared__ unsigned short ldsA[128 * 128];
  __shared__ unsigned short ldsB[128 * 128];
  const int row0 = blockIdx.x * 128, col0 = blockIdx.y * 128;
  const int tid = threadIdx.x, lane = tid & 63, wave = tid >> 6;
  const int quad = lane >> 4, sw = lane & 15;
  const unsigned short* aP[8];
  const unsigned short* bP[8];
#pragma unroll
  for (int c = 0; c < 8; ++c) {
    const int rl = wave * 32 + c * 4 + quad;
    const int srcoff = ((sw ^ (rl & 15)) << 3);
    aP[c] = h1in + (size_t)(row0 + rl) * H1 + srcoff;
    bP[c] = W2T + (size_t)(col0 + rl) * H1 + srcoff;
  }
  f32x4 acc[4][4] = {};
  gemm_core128(aP, bP, (char*)ldsA, (char*)ldsB, H1, tid, acc);
  const int wm = wave & 1, wn = wave >> 1;
#pragma unroll
  for (int j = 0; j < 4; ++j) {
    const int n = col0 + wn * 64 + j * 16 + sw;
    const float bj = b2[n];
#pragma unroll
    for (int i = 0; i < 4; ++i) {
      const int rbase = row0 + wm * 64 + i * 16 + (quad << 2);
#pragma unroll
      for (int r = 0; r < 4; ++r) {
        float v = acc[i][j][r] + bj;
        v = fmaxf(v, 0.0f);
        hfout[(size_t)(rbase + r) * H2 + n] = f2bf(v);
      }
    }
  }
}

// ------------- GEMM3: 32x128 tiles, BK=128; out[perm[q]] = tanh(hf[perm[q]] @ W3[g] + b3[g]) ---
__global__ __launch_bounds__(256) void k_gemm3(const unsigned short* __restrict__ hf,
                                               const unsigned short* __restrict__ W3T,
                                               const float* __restrict__ b3,
                                               const int* __restrict__ off,
                                               const int* __restrict__ perm,
                                               float* __restrict__ outp) {
  __shared__ unsigned short ldsA[32 * 128];
  __shared__ unsigned short ldsB[128 * 128];
  int g, seg1, row0;
  if (!seg_map32(off, blockIdx.x, g, seg1, row0)) return;
  const int tid = threadIdx.x, lane = tid & 63, wave = tid >> 6;
  const int wm = wave & 1, wn = wave >> 1;
  const int quad = lane >> 4, sw = lane & 15;
  const unsigned short* aP[2];
  const unsigned short* bP[8];
#pragma unroll
  for (int c = 0; c < 2; ++c) {
    const int rl = wave * 8 + c * 4 + quad;
    const int srcoff = ((sw ^ (rl & 15)) << 3);
    int q = row0 + rl;
    if (q > seg1 - 1) q = seg1 - 1;
    aP[c] = hf + (size_t)perm[q] * H2 + srcoff;
  }
#pragma unroll
  for (int c = 0; c < 8; ++c) {
    const int rl = wave * 32 + c * 4 + quad;
    const int srcoff = ((sw ^ (rl & 15)) << 3);
    bP[c] = W3T + (size_t)g * A_DIM * H2 + (size_t)rl * H2 + srcoff;
  }
  char* A = (char*)ldsA;
  char* Bc = (char*)ldsB;
  const int mA = wm * 16 + sw;
  const int nB = wn * 64 + sw;
  f32x4 acc[4] = {};
  for (int k0 = 0; k0 < H2; k0 += 128) {
    __syncthreads();
#pragma unroll
    for (int c = 0; c < 2; ++c)
      async_load16(aP[c] + k0, A + (wave * 8 + c * 4) * 256);
#pragma unroll
    for (int c = 0; c < 8; ++c)
      async_load16(bP[c] + k0, Bc + (wave * 32 + c * 4) * 256);
    __syncthreads();
#pragma unroll
    for (int ks = 0; ks < 4; ++ks) {
      const int u = (((ks * 4 + quad) ^ sw) << 4);
      const bf16x8 aF = *(const bf16x8*)(A + mA * 256 + u);
      bf16x8 bF[4];
#pragma unroll
      for (int j = 0; j < 4; ++j)
        bF[j] = *(const bf16x8*)(Bc + (nB + j * 16) * 256 + u);
#pragma unroll
      for (int j = 0; j < 4; ++j)
        acc[j] = __builtin_amdgcn_mfma_f32_16x16x32_bf16(aF, bF[j], acc[j], 0, 0, 0);
    }
  }
  const float* bg = b3 + g * A_DIM;
#pragma unroll
  for (int j = 0; j < 4; ++j) {
    const int n = wn * 64 + j * 16 + sw;
    const float bj = bg[n];
    const int qbase = row0 + wm * 16 + (quad << 2);
#pragma unroll
    for (int r = 0; r < 4; ++r) {
      const int q2 = qbase + r;
      if (q2 < seg1)
        outp[(size_t)perm[q2] * A_DIM + n] = tanhf(acc[j][r] + bj);
    }
  }
}

extern "C" void kernel_launch(void* const* d_in, const int* in_sizes, int n_in,
                              void* d_out, int out_size, void* d_ws, size_t ws_size,
                              hipStream_t stream) {
  (void)in_sizes; (void)n_in; (void)out_size; (void)ws_size;
  const float* state = (const float*)d_in[0];
  const int*   idx   = (const int*)d_in[1];
  const float* W1    = (const float*)d_in[2];
  const float* b1    = (const float*)d_in[3];
  const float* W2    = (const float*)d_in[4];
  const float* b2    = (const float*)d_in[5];
  const float* W3    = (const float*)d_in[6];
  const float* b3    = (const float*)d_in[7];
  float* outp = (float*)d_out;
  char* ws = (char*)d_ws;
  int* off  = (int*)(ws + WS_OFF);
  int* perm = (int*)(ws + WS_PERM);
  unsigned short* sPerm = (unsigned short*)(ws + WS_SPERM);
  unsigned short* W1T   = (unsigned short*)(ws + WS_W1T);
  unsigned short* W2T   = (unsigned short*)(ws + WS_W2T);
  unsigned short* W3T   = (unsigned short*)(ws + WS_W3T);
  unsigned short* h1    = (unsigned short*)(ws + WS_H1);
  unsigned short* hf    = (unsigned short*)(ws + WS_HF);

  hipLaunchKernelGGL(k_pre1, dim3(1537), dim3(256), 0, stream,
                     W1, W2, W3, idx, W1T, W2T, W3T, perm, off);
  hipLaunchKernelGGL(k_gather, dim3(B_ROWS / 2), dim3(256), 0, stream, state, perm, sPerm);
  hipLaunchKernelGGL(k_gemm1, dim3(72, 8), dim3(256), 0, stream, sPerm, W1T, b1, off, h1);
  hipLaunchKernelGGL(k_gemm2, dim3(64, 8), dim3(256), 0, stream, h1, W2T, b2, hf);
  hipLaunchKernelGGL(k_gemm3, dim3(264), dim3(256), 0, stream, hf, W3T, b3, off, perm, outp);
}

// Round 4
// 155.618 us; speedup vs baseline: 1.3185x; 1.1071x over previous
//
#include <hip/hip_runtime.h>
#include <math.h>

#define G_GAMES 8
#define D_IN 512
#define H1 1024
#define H2 1024
#define A_DIM 128
#define B_ROWS 8192

typedef short bf16x8 __attribute__((ext_vector_type(8)));
typedef float f32x4 __attribute__((ext_vector_type(4)));

// ---------- workspace layout (bytes) ----------
#define WS_OFF   0u
#define WS_PERM  256u
#define WS_SPERM 33280u                               // B*D_IN bf16
#define WS_W1T   (WS_SPERM + B_ROWS*D_IN*2u)          // G*H1*D_IN bf16
#define WS_W2T   (WS_W1T + G_GAMES*D_IN*H1*2u)        // H2*H1 bf16
#define WS_W3T   (WS_W2T + (unsigned)H1*H2*2u)        // G*A*H2 bf16
#define WS_H1    (WS_W3T + G_GAMES*H2*A_DIM*2u)       // B*H1 bf16
#define WS_HF    WS_SPERM                             // aliases sPerm (dead after gemm1)

__device__ __forceinline__ unsigned short f2bf(float x) {
  union { float f; unsigned int u; } v; v.f = x;
  unsigned int r = v.u + 0x7fffu + ((v.u >> 16) & 1u);
  return (unsigned short)(r >> 16);
}

__device__ __forceinline__ void async_load16(const void* gptr, void* ldsptr) {
  __builtin_amdgcn_global_load_lds(
      (const __attribute__((address_space(1))) unsigned int*)gptr,
      (__attribute__((address_space(3))) unsigned int*)ldsptr,
      16, 0, 0);
}

// ---------------- stable counting sort (256 threads, 32 elems each) ----------------
__device__ void sort_256(const int* __restrict__ idx, int* __restrict__ perm,
                         int* __restrict__ off) {
  __shared__ int wtot[4][9];
  __shared__ int wbase[4][9];
  __shared__ int offs[9];
  const int t = threadIdx.x, lane = t & 63, wave = t >> 6;
  int my[32];
#pragma unroll
  for (int i = 0; i < 8; ++i) {
    const int4 a = *(const int4*)(idx + t * 32 + i * 4);
    my[i*4+0] = a.x; my[i*4+1] = a.y; my[i*4+2] = a.z; my[i*4+3] = a.w;
  }
  int local[8] = {0,0,0,0,0,0,0,0};
#pragma unroll
  for (int i = 0; i < 32; ++i) local[my[i]]++;
  int incl[8];
#pragma unroll
  for (int g = 0; g < 8; ++g) {
    int v = local[g];
#pragma unroll
    for (int d = 1; d < 64; d <<= 1) {
      const int n = __shfl_up(v, d);
      if (lane >= d) v += n;
    }
    incl[g] = v;
  }
  if (lane == 63) {
#pragma unroll
    for (int g = 0; g < 8; ++g) wtot[wave][g] = incl[g];
  }
  __syncthreads();
  if (t < 8) {
    int s = 0;
#pragma unroll
    for (int w = 0; w < 4; ++w) { wbase[w][t] = s; s += wtot[w][t]; }
    wtot[0][t] = s;
  }
  __syncthreads();
  if (t == 0) {
    int s = 0;
#pragma unroll
    for (int g = 0; g < 8; ++g) { offs[g] = s; off[g] = s; s += wtot[0][g]; }
    offs[8] = s; off[8] = s;
  }
  __syncthreads();
  int start[8];
#pragma unroll
  for (int g = 0; g < 8; ++g)
    start[g] = offs[g] + wbase[wave][g] + (incl[g] - local[g]);
#pragma unroll
  for (int i = 0; i < 32; ++i) {
    const int g = my[i];
    perm[start[g]++] = t * 32 + i;
  }
}

// ------------- fp32 [R][C] -> bf16 [C][R] transpose tile (64x64) -------------
__device__ void trans_tile(const float* __restrict__ in,
                           unsigned short* __restrict__ out,
                           int R, int C, int xt, int yt, int z) {
  in  += (size_t)z * R * C;
  out += (size_t)z * R * C;
  __shared__ float tile[64][65];
  const int c0 = xt * 64, r0 = yt * 64;
  const int tx = threadIdx.x & 63, ty = threadIdx.x >> 6;
#pragma unroll
  for (int rr = ty; rr < 64; rr += 4)
    tile[rr][tx] = in[(size_t)(r0 + rr) * C + c0 + tx];
  __syncthreads();
#pragma unroll
  for (int cc = ty; cc < 64; cc += 4)
    out[(size_t)(c0 + cc) * R + r0 + tx] = f2bf(tile[tx][cc]);
}

// blocks: [0,1024) W1, [1024,1280) W2, [1280,1536) W3, 1536 = sort
__global__ __launch_bounds__(256) void k_pre1(const float* __restrict__ W1,
                                              const float* __restrict__ W2,
                                              const float* __restrict__ W3,
                                              const int* __restrict__ idx,
                                              unsigned short* __restrict__ W1T,
                                              unsigned short* __restrict__ W2T,
                                              unsigned short* __restrict__ W3T,
                                              int* __restrict__ perm,
                                              int* __restrict__ off) {
  const int b = blockIdx.x;
  if (b < 1024) {
    const int z = b >> 7, r = b & 127;
    trans_tile(W1, W1T, D_IN, H1, r & 15, r >> 4, z);
  } else if (b < 1280) {
    const int r = b - 1024;
    trans_tile(W2, W2T, H1, H2, r & 15, r >> 4, 0);
  } else if (b < 1536) {
    const int r = (b - 1280) & 31, z = (b - 1280) >> 5;
    trans_tile(W3, W3T, H2, A_DIM, r & 1, r >> 1, z);
  } else {
    sort_256(idx, perm, off);
  }
}

// ------------- gather state rows by perm, fp32 -> bf16 -------------
__global__ __launch_bounds__(256) void k_gather(const float* __restrict__ state,
                                                const int* __restrict__ perm,
                                                unsigned short* __restrict__ sPerm) {
  const int p = blockIdx.x * 2 + (threadIdx.x >> 7);
  const int c = (threadIdx.x & 127) << 2;
  const int src = perm[p];
  const float4 v = *(const float4*)(state + (size_t)src * D_IN + c);
  ushort4 o;
  o.x = f2bf(v.x); o.y = f2bf(v.y); o.z = f2bf(v.z); o.w = f2bf(v.w);
  *(ushort4*)(sPerm + (size_t)p * D_IN + c) = o;
}

// ------------- double-buffered MFMA core: 128x128 tile, BK=64, 4 waves 2x2, 4x4 accs ----
// LDS row = 64 elems = 128 B = 8 x 16B units; physical unit = logical ^ (row&7).
// Single barrier per iter: sync (drains tile k, cheap: loads had full compute phase),
// then issue tile k+1 into other buffer, then compute tile k.
// smem layout: A0@0  A1@16K  B0@32K  B1@48K  (64 KB)
template <int KTOT>
__device__ __forceinline__ void gemm_db_core(const unsigned short* const* aP,
                                             const unsigned short* const* bP,
                                             char* smem, int tid, f32x4 acc[4][4]) {
  const int lane = tid & 63, wave = tid >> 6;
  const int wm = wave & 1, wn = wave >> 1;
  const int sw = lane & 15, quad = lane >> 4;
  const int mA = wm * 64 + sw;
  const int nB = wn * 64 + sw;
  char* A0 = smem;          char* A1 = smem + 16384;
  char* B0 = smem + 32768;  char* B1 = smem + 49152;
  const int NIT = KTOT >> 6;
#pragma unroll
  for (int c = 0; c < 4; ++c) {
    async_load16(aP[c], A0 + (wave * 32 + c * 8) * 128);
    async_load16(bP[c], B0 + (wave * 32 + c * 8) * 128);
  }
#pragma unroll 2
  for (int k = 0; k < NIT; ++k) {
    __syncthreads();
    char* A = (k & 1) ? A1 : A0;
    char* B = (k & 1) ? B1 : B0;
    if (k + 1 < NIT) {
      char* An = (k & 1) ? A0 : A1;
      char* Bn = (k & 1) ? B0 : B1;
      const int koff = (k + 1) << 6;
#pragma unroll
      for (int c = 0; c < 4; ++c) {
        async_load16(aP[c] + koff, An + (wave * 32 + c * 8) * 128);
        async_load16(bP[c] + koff, Bn + (wave * 32 + c * 8) * 128);
      }
    }
#pragma unroll
    for (int ks = 0; ks < 2; ++ks) {
      const int u = ((((ks << 2) + quad) ^ (sw & 7)) << 4);
      bf16x8 aF[4], bF[4];
#pragma unroll
      for (int i = 0; i < 4; ++i) {
        aF[i] = *(const bf16x8*)(A + (mA + i * 16) * 128 + u);
        bF[i] = *(const bf16x8*)(B + (nB + i * 16) * 128 + u);
      }
#pragma unroll
      for (int i = 0; i < 4; ++i)
#pragma unroll
        for (int j = 0; j < 4; ++j)
          acc[i][j] = __builtin_amdgcn_mfma_f32_16x16x32_bf16(aF[i], bF[j], acc[i][j], 0, 0, 0);
    }
  }
}

__device__ __forceinline__ bool seg_map(const int* __restrict__ off, int T,
                                        int& g, int& seg1, int& row0) {
  int base = 0;
  for (int gg = 0; gg < 8; ++gg) {
    const int s = off[gg], e = off[gg + 1];
    const int nt = (e - s + 127) >> 7;
    if (T < base + nt) { g = gg; seg1 = e; row0 = s + (T - base) * 128; return true; }
    base += nt;
  }
  return false;
}

__device__ __forceinline__ bool seg_map32(const int* __restrict__ off, int T,
                                          int& g, int& seg1, int& row0) {
  int base = 0;
  for (int gg = 0; gg < 8; ++gg) {
    const int s = off[gg], e = off[gg + 1];
    const int nt = (e - s + 31) >> 5;
    if (T < base + nt) { g = gg; seg1 = e; row0 = s + (T - base) * 32; return true; }
    base += nt;
  }
  return false;
}

// Epilogue: stage bf16 C-tile in LDS (row stride 264 B breaks write conflicts),
// then copy out as full 256-B row segments (16 B/lane) — no partial-line RMW.
// rowValid: rows [0, vrows) stored.
__device__ __forceinline__ void epilogue_bf16(char* smem, const f32x4 acc[4][4],
                                              const float* bj, int tid,
                                              unsigned short* __restrict__ outp,
                                              size_t ldOut, int row0, int col0,
                                              int vrows) {
  const int lane = tid & 63, wave = tid >> 6;
  const int wm = wave & 1, wn = wave >> 1;
  const int sw = lane & 15, quad = lane >> 4;
  __syncthreads();  // all LDS reads of K-loop done before overwrite
#pragma unroll
  for (int i = 0; i < 4; ++i)
#pragma unroll
    for (int j = 0; j < 4; ++j)
#pragma unroll
      for (int r = 0; r < 4; ++r) {
        const int row = wm * 64 + i * 16 + quad * 4 + r;
        const int col = wn * 64 + j * 16 + sw;
        const float v = fmaxf(acc[i][j][r] + bj[j], 0.0f);
        *(unsigned short*)(smem + row * 264 + col * 2) = f2bf(v);
      }
  __syncthreads();
#pragma unroll
  for (int q = 0; q < 8; ++q) {
    const int idxq = q * 256 + tid;   // 2048 chunks: 128 rows x 16 chunks of 16B
    const int row = idxq >> 4, ch = idxq & 15;
    if (row < vrows) {
      const uint2 lo = *(const uint2*)(smem + row * 264 + ch * 16);
      const uint2 hi = *(const uint2*)(smem + row * 264 + ch * 16 + 8);
      uint4 v; v.x = lo.x; v.y = lo.y; v.z = hi.x; v.w = hi.y;
      *(uint4*)((char*)outp + ((size_t)(row0 + row) * ldOut + col0 + ch * 8) * 2) = v;
    }
  }
}

// ------------- GEMM1: h1[p] = relu(sPerm[p] @ W1[g] + b1[g]), grouped -------------
__global__ __launch_bounds__(256) void k_gemm1(const unsigned short* __restrict__ sPerm,
                                               const unsigned short* __restrict__ W1T,
                                               const float* __restrict__ b1,
                                               const int* __restrict__ off,
                                               unsigned short* __restrict__ h1out) {
  __shared__ char smem[65536];
  int g, seg1, row0;
  if (!seg_map(off, blockIdx.x, g, seg1, row0)) return;
  const int col0 = blockIdx.y * 128;
  const int tid = threadIdx.x, lane = tid & 63, wave = tid >> 6;
  const int gcol = ((lane & 7) ^ (lane >> 3)) << 3;
  const unsigned short* aP[4];
  const unsigned short* bP[4];
#pragma unroll
  for (int c = 0; c < 4; ++c) {
    const int rl = wave * 32 + c * 8 + (lane >> 3);
    int p = row0 + rl;
    if (p > seg1 - 1) p = seg1 - 1;
    aP[c] = sPerm + (size_t)p * D_IN + gcol;
    bP[c] = W1T + (size_t)g * H1 * D_IN + (size_t)(col0 + rl) * D_IN + gcol;
  }
  f32x4 acc[4][4] = {};
  gemm_db_core<D_IN>(aP, bP, smem, tid, acc);
  const int wn = wave >> 1, sw = lane & 15;
  const float* bg = b1 + g * H1;
  float bj[4];
#pragma unroll
  for (int j = 0; j < 4; ++j) bj[j] = bg[col0 + wn * 64 + j * 16 + sw];
  const int vrows = min(128, seg1 - row0);
  epilogue_bf16(smem, acc, bj, tid, h1out, H1, row0, col0, vrows);
}

// ------------- GEMM2: h_f = relu(h1 @ W2 + b2) -------------
__global__ __launch_bounds__(256) void k_gemm2(const unsigned short* __restrict__ h1in,
                                               const unsigned short* __restrict__ W2T,
                                               const float* __restrict__ b2,
                                               unsigned short* __restrict__ hfout) {
  __shared__ char smem[65536];
  const int row0 = blockIdx.x * 128, col0 = blockIdx.y * 128;
  const int tid = threadIdx.x, lane = tid & 63, wave = tid >> 6;
  const int gcol = ((lane & 7) ^ (lane >> 3)) << 3;
  const unsigned short* aP[4];
  const unsigned short* bP[4];
#pragma unroll
  for (int c = 0; c < 4; ++c) {
    const int rl = wave * 32 + c * 8 + (lane >> 3);
    aP[c] = h1in + (size_t)(row0 + rl) * H1 + gcol;
    bP[c] = W2T + (size_t)(col0 + rl) * H1 + gcol;
  }
  f32x4 acc[4][4] = {};
  gemm_db_core<H1>(aP, bP, smem, tid, acc);
  const int wn = wave >> 1, sw = lane & 15;
  float bj[4];
#pragma unroll
  for (int j = 0; j < 4; ++j) bj[j] = b2[col0 + wn * 64 + j * 16 + sw];
  epilogue_bf16(smem, acc, bj, tid, hfout, H2, row0, col0, 128);
}

// ------------- GEMM3: 32x128 tiles, dbuf BK=64; out[perm[q]] = tanh(...) -------------
// smem: A0@0(4K) A1@4K B0@8K(16K) B1@24K ; C-stage overlays @0 (32 x 528 B = 16.5 KB)
__global__ __launch_bounds__(256) void k_gemm3(const unsigned short* __restrict__ hf,
                                               const unsigned short* __restrict__ W3T,
                                               const float* __restrict__ b3,
                                               const int* __restrict__ off,
                                               const int* __restrict__ perm,
                                               float* __restrict__ outp) {
  __shared__ char smem[40960];
  int g, seg1, row0;
  if (!seg_map32(off, blockIdx.x, g, seg1, row0)) return;
  const int tid = threadIdx.x, lane = tid & 63, wave = tid >> 6;
  const int wm = wave & 1, wn = wave >> 1;
  const int sw = lane & 15, quad = lane >> 4;
  const int gcol = ((lane & 7) ^ (lane >> 3)) << 3;
  // A: wave w stages rows w*8 .. w*8+8 (one 1KB instr per wave)
  int q0 = row0 + wave * 8 + (lane >> 3);
  if (q0 > seg1 - 1) q0 = seg1 - 1;
  const unsigned short* aP = hf + (size_t)perm[q0] * H2 + gcol;
  const unsigned short* bP[4];
#pragma unroll
  for (int c = 0; c < 4; ++c) {
    const int rl = wave * 32 + c * 8 + (lane >> 3);
    bP[c] = W3T + (size_t)g * A_DIM * H2 + (size_t)rl * H2 + gcol;
  }
  char* A0 = smem;         char* A1 = smem + 4096;
  char* B0 = smem + 8192;  char* B1 = smem + 24576;
  const int mA = wm * 16 + sw;
  const int nB = wn * 64 + sw;
  f32x4 acc[4] = {};
  async_load16(aP, A0 + (wave * 8) * 128);
#pragma unroll
  for (int c = 0; c < 4; ++c)
    async_load16(bP[c], B0 + (wave * 32 + c * 8) * 128);
#pragma unroll 2
  for (int k = 0; k < (H2 >> 6); ++k) {
    __syncthreads();
    char* A = (k & 1) ? A1 : A0;
    char* B = (k & 1) ? B1 : B0;
    if (k + 1 < (H2 >> 6)) {
      char* An = (k & 1) ? A0 : A1;
      char* Bn = (k & 1) ? B0 : B1;
      const int koff = (k + 1) << 6;
      async_load16(aP + koff, An + (wave * 8) * 128);
#pragma unroll
      for (int c = 0; c < 4; ++c)
        async_load16(bP[c] + koff, Bn + (wave * 32 + c * 8) * 128);
    }
#pragma unroll
    for (int ks = 0; ks < 2; ++ks) {
      const int u = ((((ks << 2) + quad) ^ (sw & 7)) << 4);
      const bf16x8 aF = *(const bf16x8*)(A + mA * 128 + u);
      bf16x8 bF[4];
#pragma unroll
      for (int j = 0; j < 4; ++j)
        bF[j] = *(const bf16x8*)(B + (nB + j * 16) * 128 + u);
#pragma unroll
      for (int j = 0; j < 4; ++j)
        acc[j] = __builtin_amdgcn_mfma_f32_16x16x32_bf16(aF, bF[j], acc[j], 0, 0, 0);
    }
  }
  // epilogue: fp32 C 32x128, LDS row stride 528 B, then 512-B coalesced row stores
  const float* bg = b3 + g * A_DIM;
  float bj[4];
#pragma unroll
  for (int j = 0; j < 4; ++j) bj[j] = bg[wn * 64 + j * 16 + sw];
  __syncthreads();
#pragma unroll
  for (int j = 0; j < 4; ++j)
#pragma unroll
    for (int r = 0; r < 4; ++r) {
      const int row = wm * 16 + quad * 4 + r;
      const int col = wn * 64 + j * 16 + sw;
      *(float*)(smem + row * 528 + col * 4) = tanhf(acc[j][r] + bj[j]);
    }
  __syncthreads();
#pragma unroll
  for (int qq = 0; qq < 4; ++qq) {
    const int idxq = qq * 256 + tid;  // 1024 chunks: 32 rows x 32 chunks of 16B
    const int row = idxq >> 5, ch = idxq & 31;
    if (row0 + row < seg1) {
      const uint4 v = *(const uint4*)(smem + row * 528 + ch * 16);
      *(uint4*)((char*)outp + ((size_t)perm[row0 + row] * A_DIM + ch * 4) * 4) = v;
    }
  }
}

extern "C" void kernel_launch(void* const* d_in, const int* in_sizes, int n_in,
                              void* d_out, int out_size, void* d_ws, size_t ws_size,
                              hipStream_t stream) {
  (void)in_sizes; (void)n_in; (void)out_size; (void)ws_size;
  const float* state = (const float*)d_in[0];
  const int*   idx   = (const int*)d_in[1];
  const float* W1    = (const float*)d_in[2];
  const float* b1    = (const float*)d_in[3];
  const float* W2    = (const float*)d_in[4];
  const float* b2    = (const float*)d_in[5];
  const float* W3    = (const float*)d_in[6];
  const float* b3    = (const float*)d_in[7];
  float* outp = (float*)d_out;
  char* ws = (char*)d_ws;
  int* off  = (int*)(ws + WS_OFF);
  int* perm = (int*)(ws + WS_PERM);
  unsigned short* sPerm = (unsigned short*)(ws + WS_SPERM);
  unsigned short* W1T   = (unsigned short*)(ws + WS_W1T);
  unsigned short* W2T   = (unsigned short*)(ws + WS_W2T);
  unsigned short* W3T   = (unsigned short*)(ws + WS_W3T);
  unsigned short* h1    = (unsigned short*)(ws + WS_H1);
  unsigned short* hf    = (unsigned short*)(ws + WS_HF);

  hipLaunchKernelGGL(k_pre1, dim3(1537), dim3(256), 0, stream,
                     W1, W2, W3, idx, W1T, W2T, W3T, perm, off);
  hipLaunchKernelGGL(k_gather, dim3(B_ROWS / 2), dim3(256), 0, stream, state, perm, sPerm);
  hipLaunchKernelGGL(k_gemm1, dim3(72, 8), dim3(256), 0, stream, sPerm, W1T, b1, off, h1);
  hipLaunchKernelGGL(k_gemm2, dim3(64, 8), dim3(256), 0, stream, h1, W2T, b2, hf);
  hipLaunchKernelGGL(k_gemm3, dim3(264), dim3(256), 0, stream, hf, W3T, b3, off, perm, outp);
}